// Round 8
// baseline (184.526 us; speedup 1.0000x reference)
//
#include <hip/hip_runtime.h>
#include <math.h>

#define D 128
#define TWO_D 256
#define CAP 64           // fine bucket capacity/row; deg~Poisson(12), P(>=64)~1e-27
#define CCAP 3584        // coarse bucket capacity (exp ~3061, +9.5 sigma)
#define CHUNK 2048       // edges per bin block (8/thread); 293 blocks spread the
                         // LDS-atomic work over ~all CUs (r3: 4096 halved CUs, +10us)

typedef __bf16 v8bf __attribute__((ext_vector_type(8)));
typedef float  v4f  __attribute__((ext_vector_type(4)));
typedef unsigned short v8us __attribute__((ext_vector_type(8)));

// ============================ ws layout (bytes) =============================
#define OFF_CNT      0u
#define OFF_COLBUF   200192u
#define OFF_CCNT     6600192u
#define OFF_COARSE   6601216u
#define OFF_WBF16    10271232u
#define OFF_EMBB     10336768u
#define WS_TIER_A    23136768u

// ---------------------------------------------------------------------------
// K1: FUSED fp32->bf16 conversion + COARSE edge binning (r4/r6 proven; the
// r7 split cost 12.6us of lost overlap). Single-pass LDS histogram: per-edge
// position comes from the pass-1 atomic return ((r<<12)|lp in registers).
// ---------------------------------------------------------------------------
__global__ __launch_bounds__(256) void k_cvt_bin(
    const float* __restrict__ emb, const float* __restrict__ W,
    const int* __restrict__ edges,
    __bf16* __restrict__ embb, __bf16* __restrict__ Wb,
    unsigned int* __restrict__ ccnt, unsigned int* __restrict__ coarse,
    int nEmb8, int nW8, int E, int binB, int NB)
{
    if ((int)blockIdx.x < binB) {
        __shared__ unsigned int hist[256];
        __shared__ unsigned int base[256];
        int tid = threadIdx.x;
        int e0  = blockIdx.x * CHUNK;
        hist[tid] = 0;
        __syncthreads();

        unsigned rs[CHUNK / 256];       // (r<<12) | lp ; r<2^20, lp<2048
        #pragma unroll
        for (int k = 0; k < CHUNK / 256; ++k) {
            int e = e0 + k * 256 + tid;
            if (e < E) {
                unsigned r  = (unsigned)edges[e];
                unsigned lp = atomicAdd(&hist[r >> 8], 1u);
                rs[k] = (r << 12) | lp;
            }
        }
        __syncthreads();
        if (tid < NB) {
            unsigned h = hist[tid];
            base[tid] = h ? atomicAdd(&ccnt[tid], h) : 0u;
        }
        __syncthreads();
        #pragma unroll
        for (int k = 0; k < CHUNK / 256; ++k) {
            int e = e0 + k * 256 + tid;
            if (e < E) {
                unsigned pk = rs[k];
                unsigned r  = pk >> 12;
                unsigned lp = pk & 0xFFFu;
                unsigned c  = (unsigned)edges[E + e];
                int bk = r >> 8;
                unsigned slot = base[bk] + lp;
                if (slot < CCAP)
                    coarse[(size_t)bk * CCAP + slot] = ((r & 255u) << 16) | c;
            }
        }
    } else {
        int tid = ((int)blockIdx.x - binB) * 256 + threadIdx.x;
        if (tid < nEmb8 + nW8) {
            const float* src;
            __bf16* dst;
            if (tid < nEmb8) { src = emb + (size_t)tid * 8; dst = embb + (size_t)tid * 8; }
            else { int j = (tid - nEmb8) * 8; src = W + j; dst = Wb + j; }
            float4 f0 = *(const float4*)(src);
            float4 f1 = *(const float4*)(src + 4);
            v8bf v;
            v[0] = (__bf16)f0.x; v[1] = (__bf16)f0.y; v[2] = (__bf16)f0.z; v[3] = (__bf16)f0.w;
            v[4] = (__bf16)f1.x; v[5] = (__bf16)f1.y; v[6] = (__bf16)f1.z; v[7] = (__bf16)f1.w;
            *(v8bf*)dst = v;
        }
    }
}

// ---------------------------------------------------------------------------
// K2: fine CSR build, one block per coarse bucket (256 rows). LDS-only
// atomics + dense coalesced tile writeback.  [r2 proven]
// ---------------------------------------------------------------------------
__global__ __launch_bounds__(256) void k_fine(
    const unsigned int* __restrict__ coarse,
    const unsigned int* __restrict__ ccnt,
    int* __restrict__ cnt, unsigned short* __restrict__ colbuf, int N)
{
    __shared__ __align__(16) unsigned short ftile[256 * CAP];   // 32 KB
    __shared__ unsigned int fcnt[256];
    int tid = threadIdx.x;
    int b   = blockIdx.x;
    int r0  = b << 8;
    fcnt[tid] = 0;
    __syncthreads();

    unsigned mc = ccnt[b];
    if (mc > CCAP) mc = CCAP;
    for (unsigned i = tid; i < mc; i += 256) {
        unsigned p = coarse[(size_t)b * CCAP + i];
        unsigned rlo = p >> 16;
        unsigned c   = p & 0xFFFFu;
        unsigned lp  = atomicAdd(&fcnt[rlo], 1u);
        if (lp < CAP) ftile[rlo * CAP + lp] = (unsigned short)c;
    }
    __syncthreads();

    int r = r0 + tid;
    if (r < N) {
        unsigned d = fcnt[tid];
        cnt[r] = (int)(d > CAP ? CAP : d);
    }
    #pragma unroll
    for (int j = 0; j < 8; ++j) {
        int g  = j * 256 + tid;
        int rr = r0 + (g >> 3);
        if (rr < N)
            *(v8us*)(colbuf + (size_t)rr * CAP + (g & 7) * 8) =
                *(const v8us*)(ftile + (g >> 3) * CAP + (g & 7) * 8);
    }
}

// ---------------------------------------------------------------------------
// K3 (r8): FUSED aggregation + MFMA node kernel. Key invariant preserved:
// each wave stages and consumes ONLY its own 16 rows -> NO __syncthreads
// (DS pipe is wave-in-order). Agg results are written straight into the LDS
// staging tile (granules 16..31, XOR-swizzled), never to global: eliminates
// the 12.5MB agg write + 12.8MB node re-read + one launch, and overlaps
// late waves' gathers with early waves' MFMA. Gather line count (the r7
// MSHR-latency floor, ~40us) is unchanged by design.
// A-tile XOR-swizzle: granule(m,g) at m*32 + (g ^ (m&7)).
// MFMA D layout: col=lane&15 (feat), row=quad*4+reg (node)  [verified].
// ---------------------------------------------------------------------------
__global__ __launch_bounds__(256) void gcn_fused(
    const __bf16* __restrict__ embb,
    const unsigned short* __restrict__ colbuf,
    const int* __restrict__ cnt,
    const __bf16* __restrict__ Wb,
    const float* __restrict__ bias,
    const float* __restrict__ gamma,
    const float* __restrict__ beta,
    float* __restrict__ out, int N)
{
    __shared__ __align__(16) __bf16 xt[64 * 256];   // 32 KB

    int t    = threadIdx.x;
    int wave = t >> 6;
    int lane = t & 63;
    int il   = lane & 15;
    int slot = lane >> 4;          // 0..3
    int n0   = blockIdx.x * 64;

    // ---- stage emb half: this wave's 16 rows x granules 0..15 ----
    #pragma unroll
    for (int j = 0; j < 4; ++j) {
        int gf = j * 64 + lane;        // 0..255
        int ml = gf >> 4;              // 0..15
        int g  = gf & 15;              // 0..15
        int m  = wave * 16 + ml;
        int n  = n0 + m;
        v8bf v;
        if (n < N) {
            v = *(const v8bf*)(embb + (size_t)n * D + g * 8);
        } else {
            #pragma unroll
            for (int q = 0; q < 8; ++q) v[q] = (__bf16)0.0f;
        }
        *(v8bf*)(xt + (m * 32 + (g ^ (m & 7))) * 8) = v;
    }

    // ---- agg phase: one full wave per node, 16 nodes serially ----
    for (int ml = 0; ml < 16; ++ml) {
        int m = wave * 16 + ml;
        int n = n0 + m;
        if (n < N) {
            // query row from LDS (staged verbatim -> identical numerics)
            v8bf a8 = *(const v8bf*)(xt + (m * 32 + (il ^ (m & 7))) * 8);
            float af[8];
            #pragma unroll
            for (int q = 0; q < 8; ++q) af[q] = (float)a8[q];

            float acc[8];
            #pragma unroll
            for (int q = 0; q < 8; ++q) acc[q] = 0.f;
            float den = 0.f;

            int deg = cnt[n];
            if (deg > CAP) deg = CAP;
            const unsigned short* row = colbuf + (size_t)n * CAP;
            int nb = (deg + 7) >> 3;

            for (int b = 0; b < nb; ++b) {
                int e   = b * 8;
                int rem = deg - e;
                bool v0 = (slot < rem);
                bool v1 = (slot + 4 < rem);
                int i0 = v0 ? (int)row[e + slot]     : 0;
                int i1 = v1 ? (int)row[e + slot + 4] : 0;
                v8bf r0 = *(const v8bf*)(embb + (size_t)i0 * D + il * 8);
                v8bf r1 = *(const v8bf*)(embb + (size_t)i1 * D + il * 8);
                float f0[8], f1[8];
                #pragma unroll
                for (int q = 0; q < 8; ++q) { f0[q] = (float)r0[q]; f1[q] = (float)r1[q]; }
                float t0 = 0.f, t1 = 0.f;
                #pragma unroll
                for (int q = 0; q < 8; ++q) { t0 += af[q] * f0[q]; t1 += af[q] * f1[q]; }
                #pragma unroll
                for (int off = 1; off <= 8; off <<= 1) {
                    t0 += __shfl_xor(t0, off, 16);
                    t1 += __shfl_xor(t1, off, 16);
                }
                float w0 = v0 ? __expf(t0) : 0.f;
                float w1 = v1 ? __expf(t1) : 0.f;
                #pragma unroll
                for (int q = 0; q < 8; ++q) acc[q] += w0 * f0[q] + w1 * f1[q];
                den += w0 + w1;
            }

            // combine 4 slots (butterfly across lanes 16/32)
            #pragma unroll
            for (int q = 0; q < 8; ++q) {
                acc[q] += __shfl_xor(acc[q], 16, 64);
                acc[q] += __shfl_xor(acc[q], 32, 64);
            }
            den += __shfl_xor(den, 16, 64);
            den += __shfl_xor(den, 32, 64);

            if (slot == 0) {
                float inv = 1.0f / (den + 1e-20f);
                v8bf r;
                #pragma unroll
                for (int q = 0; q < 8; ++q) r[q] = (__bf16)(acc[q] * inv);
                *(v8bf*)(xt + (m * 32 + ((16 + il) ^ (m & 7))) * 8) = r;
            }
        } else {
            if (slot == 0) {
                v8bf z;
                #pragma unroll
                for (int q = 0; q < 8; ++q) z[q] = (__bf16)0.0f;
                *(v8bf*)(xt + (m * 32 + ((16 + il) ^ (m & 7))) * 8) = z;
            }
        }
    }
    // no barrier: each wave reads only rows it wrote (DS in-order per wave)

    // ---- MFMA phase ----
    int mrow = lane & 15;
    int quad = lane >> 4;
    int mloc = wave * 16 + mrow;

    v8bf a[8];
    #pragma unroll
    for (int kt = 0; kt < 8; ++kt) {
        int g = (kt * 4 + quad) ^ (mloc & 7);
        a[kt] = *(const v8bf*)(xt + (mloc * 32 + g) * 8);
    }

    float bi[8], gm[8], bt[8];
    #pragma unroll
    for (int ft = 0; ft < 8; ++ft) {
        int f = ft * 16 + mrow;
        bi[ft] = bias[f]; gm[ft] = gamma[f]; bt[ft] = beta[f];
    }

    v4f accf[8];
    #pragma unroll
    for (int ft = 0; ft < 8; ++ft)
        #pragma unroll
        for (int r = 0; r < 4; ++r) accf[ft][r] = 0.0f;

    #pragma unroll
    for (int kt = 0; kt < 8; ++kt) {
        #pragma unroll
        for (int ft = 0; ft < 8; ++ft) {
            v8bf b = *(const v8bf*)(Wb + (ft * 16 + mrow) * TWO_D + kt * 32 + quad * 8);
            accf[ft] = __builtin_amdgcn_mfma_f32_16x16x32_bf16(a[kt], b, accf[ft], 0, 0, 0);
        }
    }

    #pragma unroll
    for (int ft = 0; ft < 8; ++ft)
        #pragma unroll
        for (int r = 0; r < 4; ++r) accf[ft][r] += bi[ft];

    #pragma unroll
    for (int r = 0; r < 4; ++r) {
        float s = 0.f, s2 = 0.f;
        #pragma unroll
        for (int ft = 0; ft < 8; ++ft) {
            float x = accf[ft][r];
            s += x; s2 += x * x;
        }
        #pragma unroll
        for (int off = 1; off <= 8; off <<= 1) {
            s  += __shfl_xor(s,  off, 64);
            s2 += __shfl_xor(s2, off, 64);
        }
        float mu  = s * (1.0f / 128.0f);
        float var = s2 * (1.0f / 128.0f) - mu * mu;
        float ivn = rsqrtf(var + 1e-5f);
        int n = n0 + wave * 16 + quad * 4 + r;
        if (n < N) {
            #pragma unroll
            for (int ft = 0; ft < 8; ++ft) {
                int f = ft * 16 + mrow;
                out[(size_t)n * D + f] = (accf[ft][r] - mu) * ivn * gm[ft] + bt[ft];
            }
        }
    }
}

// ===========================================================================
// Tier C fallback (round-1 atomic path) if ws too small
// ===========================================================================
__global__ __launch_bounds__(256) void gcn_edge_attn(
    const float* __restrict__ emb, const int* __restrict__ edges,
    float* __restrict__ agg, float* __restrict__ denom, int E) {
    int e    = (int)((blockIdx.x * 256u + threadIdx.x) >> 6);
    int lane = threadIdx.x & 63;
    if (e >= E) return;
    int row = edges[e];
    int col = edges[E + e];
    const float2 a = *(const float2*)(emb + (size_t)row * D + lane * 2);
    const float2 c = *(const float2*)(emb + (size_t)col * D + lane * 2);
    float s = a.x * c.x + a.y * c.y;
    #pragma unroll
    for (int off = 32; off >= 1; off >>= 1) s += __shfl_xor(s, off, 64);
    float attn = expf(s);
    float* dst = agg + (size_t)row * D + lane * 2;
    unsafeAtomicAdd(dst,     attn * c.x);
    unsafeAtomicAdd(dst + 1, attn * c.y);
    if (lane == 0) unsafeAtomicAdd(denom + row, attn);
}

__global__ __launch_bounds__(256) void gcn_node_fallback(
    const float* __restrict__ emb, const float* __restrict__ W,
    const float* __restrict__ bias, const float* __restrict__ gamma,
    const float* __restrict__ beta, const float* __restrict__ denom,
    float* __restrict__ out, int N) {
    __shared__ float scat[2][TWO_D];
    __shared__ float sred[2][4];
    int tid  = threadIdx.x;
    int g    = tid >> 7;
    int o    = tid & 127;
    int lane = tid & 63;
    int wig  = (tid >> 6) & 1;
    for (int n0 = blockIdx.x * 2; n0 < N; n0 += gridDim.x * 2) {
        int n = n0 + g;
        bool act = (n < N);
        if (act) {
            float ev  = emb[(size_t)n * D + o];
            float inv = 1.0f / (denom[n] + 1e-20f);
            scat[g][o]     = ev;
            scat[g][D + o] = out[(size_t)n * D + o] * inv;
        }
        __syncthreads();
        float acc = 0.f;
        if (act) {
            const float4* wr = (const float4*)(W + (size_t)o * TWO_D);
            #pragma unroll 4
            for (int k4 = 0; k4 < TWO_D / 4; ++k4) {
                float4 w = wr[k4];
                float4 a = *(const float4*)(&scat[g][k4 * 4]);
                acc += w.x * a.x + w.y * a.y + w.z * a.z + w.w * a.w;
            }
            acc += bias[o];
        }
        float s = acc, s2 = acc * acc;
        #pragma unroll
        for (int off = 32; off >= 1; off >>= 1) {
            s  += __shfl_xor(s,  off, 64);
            s2 += __shfl_xor(s2, off, 64);
        }
        if (lane == 0) { sred[g][wig * 2] = s; sred[g][wig * 2 + 1] = s2; }
        __syncthreads();
        if (act) {
            float ts  = sred[g][0] + sred[g][2];
            float ts2 = sred[g][1] + sred[g][3];
            float mu  = ts * (1.0f / 128.0f);
            float var = ts2 * (1.0f / 128.0f) - mu * mu;
            float inv = rsqrtf(var + 1e-5f);
            out[(size_t)n * D + o] = (acc - mu) * inv * gamma[o] + beta[o];
        }
        __syncthreads();
    }
}

// ---------------------------------------------------------------------------
extern "C" void kernel_launch(void* const* d_in, const int* in_sizes, int n_in,
                              void* d_out, int out_size, void* d_ws, size_t ws_size,
                              hipStream_t stream) {
    const float* emb   = (const float*)d_in[0];
    const int*   edges = (const int*)  d_in[1];
    const float* W     = (const float*)d_in[2];
    const float* bias  = (const float*)d_in[3];
    const float* gamma = (const float*)d_in[4];
    const float* beta  = (const float*)d_in[5];
    float* out = (float*)d_out;

    int N = in_sizes[0] / D;        // 50000
    int E = in_sizes[1] / 2;        // 600000

    if (ws_size >= (size_t)WS_TIER_A) {
        char* ws = (char*)d_ws;
        int*            cnt    = (int*)            (ws + OFF_CNT);
        unsigned short* colbuf = (unsigned short*) (ws + OFF_COLBUF);
        unsigned int*   ccnt   = (unsigned int*)   (ws + OFF_CCNT);
        unsigned int*   coarse = (unsigned int*)   (ws + OFF_COARSE);
        __bf16*         Wb     = (__bf16*)         (ws + OFF_WBF16);
        __bf16*         embb   = (__bf16*)         (ws + OFF_EMBB);

        int nEmb8 = N * D / 8;                        // 800000
        int nW8   = D * TWO_D / 8;                    // 4096
        int cvtB  = (nEmb8 + nW8 + 255) / 256;        // 3142
        int binB  = (E + CHUNK - 1) / CHUNK;          // 293
        int NB    = (N + 255) >> 8;                   // 196

        hipMemsetAsync(ccnt, 0, 1024, stream);
        k_cvt_bin<<<binB + cvtB, 256, 0, stream>>>(
            emb, W, edges, embb, Wb, ccnt, coarse, nEmb8, nW8, E, binB, NB);
        k_fine   <<<NB, 256, 0, stream>>>(coarse, ccnt, cnt, colbuf, N);
        gcn_fused<<<(N + 63) / 64, 256, 0, stream>>>(embb, colbuf, cnt, Wb,
                                                     bias, gamma, beta, out, N);
    } else {
        float* denom = (float*)d_ws;
        hipMemsetAsync(out,   0, (size_t)N * D * sizeof(float), stream);
        hipMemsetAsync(denom, 0, (size_t)N * sizeof(float), stream);
        gcn_edge_attn<<<(E + 3) / 4, 256, 0, stream>>>(emb, edges, out, denom, E);
        gcn_node_fallback<<<512, 256, 0, stream>>>(emb, W, bias, gamma, beta,
                                                   denom, out, N);
    }
}

// Round 9
// 170.031 us; speedup vs baseline: 1.0852x; 1.0852x over previous
//
#include <hip/hip_runtime.h>
#include <math.h>

#define D 128
#define TWO_D 256
#define CAP 64           // fine bucket capacity/row; deg~Poisson(12), P(>=64)~1e-27
#define CCAP 3584        // coarse bucket capacity (exp ~3072, +9 sigma)
#define CHUNK 2048       // edges per bin block

typedef __bf16 v8bf __attribute__((ext_vector_type(8)));
typedef float  v4f  __attribute__((ext_vector_type(4)));
typedef unsigned short us4 __attribute__((ext_vector_type(4)));
typedef unsigned short v8us __attribute__((ext_vector_type(8)));

// ============================ ws layout (bytes) =============================
#define OFF_CNT      0u
#define OFF_COLBUF   200192u
#define OFF_CCNT     6600192u
#define OFF_COARSE   6601216u
#define OFF_WBF16    10271232u
#define OFF_EMBB     10336768u
#define WS_TIER_A    23136768u

// ---------------------------------------------------------------------------
// K1: FUSED fp32->bf16 conversion + COARSE edge binning.  [r2 best: 170.45us]
// Each 2048-edge block histograms into 196 coarse buckets in LDS, reserves
// with ONE global atomic per (block,bucket) (57k total), writes packed
// (rlo<<16|col) entries contiguously. Concurrent cvt blocks hide bin latency.
// ---------------------------------------------------------------------------
__global__ __launch_bounds__(256) void k_cvt_bin(
    const float* __restrict__ emb, const float* __restrict__ W,
    const int* __restrict__ edges,
    __bf16* __restrict__ embb, __bf16* __restrict__ Wb,
    unsigned int* __restrict__ ccnt, unsigned int* __restrict__ coarse,
    int nEmb8, int nW8, int E, int binB, int NB)
{
    if ((int)blockIdx.x < binB) {
        __shared__ unsigned int hist[256];
        __shared__ unsigned int base[256];
        __shared__ unsigned int run[256];
        int tid = threadIdx.x;
        int e0  = blockIdx.x * CHUNK;
        hist[tid] = 0;
        run[tid]  = 0;
        __syncthreads();

        int rs[CHUNK / 256];
        #pragma unroll
        for (int k = 0; k < CHUNK / 256; ++k) {
            int e = e0 + k * 256 + tid;
            rs[k] = -1;
            if (e < E) {
                int r = edges[e];
                rs[k] = r;
                atomicAdd(&hist[r >> 8], 1u);
            }
        }
        __syncthreads();
        if (tid < NB) {
            unsigned h = hist[tid];
            base[tid] = h ? atomicAdd(&ccnt[tid], h) : 0u;
        }
        __syncthreads();
        #pragma unroll
        for (int k = 0; k < CHUNK / 256; ++k) {
            int e = e0 + k * 256 + tid;
            if (e < E) {
                int r = rs[k];
                int c = edges[E + e];
                int bk = r >> 8;
                unsigned lp = atomicAdd(&run[bk], 1u);
                unsigned slot = base[bk] + lp;
                if (slot < CCAP)
                    coarse[(size_t)bk * CCAP + slot] =
                        ((unsigned)(r & 255) << 16) | (unsigned)c;
            }
        }
    } else {
        int tid = ((int)blockIdx.x - binB) * 256 + threadIdx.x;
        if (tid < nEmb8 + nW8) {
            const float* src;
            __bf16* dst;
            if (tid < nEmb8) { src = emb + (size_t)tid * 8; dst = embb + (size_t)tid * 8; }
            else { int j = (tid - nEmb8) * 8; src = W + j; dst = Wb + j; }
            float4 f0 = *(const float4*)(src);
            float4 f1 = *(const float4*)(src + 4);
            v8bf v;
            v[0] = (__bf16)f0.x; v[1] = (__bf16)f0.y; v[2] = (__bf16)f0.z; v[3] = (__bf16)f0.w;
            v[4] = (__bf16)f1.x; v[5] = (__bf16)f1.y; v[6] = (__bf16)f1.z; v[7] = (__bf16)f1.w;
            *(v8bf*)dst = v;
        }
    }
}

// ---------------------------------------------------------------------------
// K2: fine CSR build, one block per coarse bucket (256 rows). LDS-only
// atomics + dense coalesced tile writeback.  [r2 proven]
// ---------------------------------------------------------------------------
__global__ __launch_bounds__(256) void k_fine(
    const unsigned int* __restrict__ coarse,
    const unsigned int* __restrict__ ccnt,
    int* __restrict__ cnt, unsigned short* __restrict__ colbuf, int N)
{
    __shared__ __align__(16) unsigned short ftile[256 * CAP];   // 32 KB
    __shared__ unsigned int fcnt[256];
    int tid = threadIdx.x;
    int b   = blockIdx.x;
    int r0  = b << 8;
    fcnt[tid] = 0;
    __syncthreads();

    unsigned mc = ccnt[b];
    if (mc > CCAP) mc = CCAP;
    for (unsigned i = tid; i < mc; i += 256) {
        unsigned p = coarse[(size_t)b * CCAP + i];
        unsigned rlo = p >> 16;
        unsigned c   = p & 0xFFFFu;
        unsigned lp  = atomicAdd(&fcnt[rlo], 1u);
        if (lp < CAP) ftile[rlo * CAP + lp] = (unsigned short)c;
    }
    __syncthreads();

    int r = r0 + tid;
    if (r < N) {
        unsigned d = fcnt[tid];
        cnt[r] = (int)(d > CAP ? CAP : d);
    }
    #pragma unroll
    for (int j = 0; j < 8; ++j) {
        int g  = j * 256 + tid;
        int rr = r0 + (g >> 3);
        if (rr < N)
            *(v8us*)(colbuf + (size_t)rr * CAP + (g & 7) * 8) =
                *(const v8us*)(ftile + (g >> 3) * CAP + (g & 7) * 8);
    }
}

// ---------------------------------------------------------------------------
// K3: aggregation, bf16, 4-edge unroll. One 16-lane group per node,
// 16 nodes/block -> 3125 blocks. Max TLP: the gather phase is bound by
// outstanding-miss capacity x latency (est. r4-r7: 2.4M random 64B lines,
// ~40us floor across 7 structural variants + NT probe) -- wave count is the
// only lever that fills the miss queues.  [r2 best-measured configuration]
// ---------------------------------------------------------------------------
__global__ __launch_bounds__(256) void gcn_agg_b(
    const __bf16* __restrict__ embb,
    const unsigned short* __restrict__ colbuf,
    const int* __restrict__ cnt,
    __bf16* __restrict__ aggb,    // = (bf16*)d_out, row stride 256
    int N)
{
    int grp = threadIdx.x >> 4;
    int il  = threadIdx.x & 15;
    int n   = blockIdx.x * 16 + grp;
    if (n >= N) return;

    v8bf a8 = *(const v8bf*)(embb + (size_t)n * D + il * 8);
    float af[8];
    #pragma unroll
    for (int q = 0; q < 8; ++q) af[q] = (float)a8[q];

    float acc[8];
    #pragma unroll
    for (int q = 0; q < 8; ++q) acc[q] = 0.f;
    float den = 0.f;

    int deg = cnt[n];
    if (deg > CAP) deg = CAP;
    const unsigned short* row = colbuf + (size_t)n * CAP;

    int e = 0;
    for (; e + 3 < deg; e += 4) {
        us4 c4 = *(const us4*)(row + e);
        v8bf v0 = *(const v8bf*)(embb + (size_t)c4[0] * D + il * 8);
        v8bf v1 = *(const v8bf*)(embb + (size_t)c4[1] * D + il * 8);
        v8bf v2 = *(const v8bf*)(embb + (size_t)c4[2] * D + il * 8);
        v8bf v3 = *(const v8bf*)(embb + (size_t)c4[3] * D + il * 8);
        float vf0[8], vf1[8], vf2[8], vf3[8];
        float t0 = 0.f, t1 = 0.f, t2 = 0.f, t3 = 0.f;
        #pragma unroll
        for (int q = 0; q < 8; ++q) {
            vf0[q] = (float)v0[q]; t0 += af[q] * vf0[q];
            vf1[q] = (float)v1[q]; t1 += af[q] * vf1[q];
            vf2[q] = (float)v2[q]; t2 += af[q] * vf2[q];
            vf3[q] = (float)v3[q]; t3 += af[q] * vf3[q];
        }
        #pragma unroll
        for (int off = 1; off <= 8; off <<= 1) {
            t0 += __shfl_xor(t0, off, 16);
            t1 += __shfl_xor(t1, off, 16);
            t2 += __shfl_xor(t2, off, 16);
            t3 += __shfl_xor(t3, off, 16);
        }
        float w0 = __expf(t0), w1 = __expf(t1);
        float w2 = __expf(t2), w3 = __expf(t3);
        #pragma unroll
        for (int q = 0; q < 8; ++q)
            acc[q] += (w0 * vf0[q] + w1 * vf1[q]) + (w2 * vf2[q] + w3 * vf3[q]);
        den += (w0 + w1) + (w2 + w3);
    }
    for (; e < deg; ++e) {
        int c0 = row[e];
        v8bf v0 = *(const v8bf*)(embb + (size_t)c0 * D + il * 8);
        float vf0[8];
        float t0 = 0.f;
        #pragma unroll
        for (int q = 0; q < 8; ++q) {
            vf0[q] = (float)v0[q];
            t0 += af[q] * vf0[q];
        }
        #pragma unroll
        for (int off = 1; off <= 8; off <<= 1)
            t0 += __shfl_xor(t0, off, 16);
        float w0 = __expf(t0);
        #pragma unroll
        for (int q = 0; q < 8; ++q) acc[q] += w0 * vf0[q];
        den += w0;
    }
    float inv = 1.0f / (den + 1e-20f);
    v8bf r;
    #pragma unroll
    for (int q = 0; q < 8; ++q) r[q] = (__bf16)(acc[q] * inv);
    *(v8bf*)(aggb + (size_t)n * 256 + il * 8) = r;
}

// ---------------------------------------------------------------------------
// K4: MFMA node kernel, pure bf16 staging, NO __syncthreads (each wave
// stages and consumes only its own 16 rows; DS pipe is wave-in-order).
// A-tile XOR-swizzled 16B granules: granule(m,g) at m*32 + (g ^ (m&7)).
// D layout: col=lane&15 (feat), row=quad*4+reg (node)  [verified].
// ---------------------------------------------------------------------------
__global__ __launch_bounds__(256) void gcn_node_b(
    const __bf16* __restrict__ embb,
    const __bf16* __restrict__ Wb,
    const float* __restrict__ bias,
    const float* __restrict__ gamma,
    const float* __restrict__ beta,
    float* __restrict__ out, int N)
{
    __shared__ __align__(16) __bf16 xt[64 * 256];   // 32 KB

    int t    = threadIdx.x;
    int wave = t >> 6;
    int lane = t & 63;
    int n0   = blockIdx.x * 64;
    const __bf16* aggb = (const __bf16*)out;        // row stride 256 bf16

    #pragma unroll
    for (int j = 0; j < 8; ++j) {
        int gf = j * 64 + lane;        // 0..511
        int ml = gf >> 5;              // 0..15
        int m  = wave * 16 + ml;
        int g  = gf & 31;
        int n  = n0 + m;
        v8bf v;
        if (n < N) {
            v = (g < 16) ? *(const v8bf*)(embb + (size_t)n * D + g * 8)
                         : *(const v8bf*)(aggb + (size_t)n * 256 + (g - 16) * 8);
        } else {
            #pragma unroll
            for (int q = 0; q < 8; ++q) v[q] = (__bf16)0.0f;
        }
        *(v8bf*)(xt + (m * 32 + (g ^ (m & 7))) * 8) = v;
    }
    // no barrier: each wave reads only rows it wrote (DS in-order per wave)

    int mrow = lane & 15;
    int quad = lane >> 4;
    int mloc = wave * 16 + mrow;

    v8bf a[8];
    #pragma unroll
    for (int kt = 0; kt < 8; ++kt) {
        int g = (kt * 4 + quad) ^ (mloc & 7);
        a[kt] = *(const v8bf*)(xt + (mloc * 32 + g) * 8);
    }

    float bi[8], gm[8], bt[8];
    #pragma unroll
    for (int ft = 0; ft < 8; ++ft) {
        int f = ft * 16 + mrow;
        bi[ft] = bias[f]; gm[ft] = gamma[f]; bt[ft] = beta[f];
    }

    v4f accf[8];
    #pragma unroll
    for (int ft = 0; ft < 8; ++ft)
        #pragma unroll
        for (int r = 0; r < 4; ++r) accf[ft][r] = 0.0f;

    #pragma unroll
    for (int kt = 0; kt < 8; ++kt) {
        #pragma unroll
        for (int ft = 0; ft < 8; ++ft) {
            v8bf b = *(const v8bf*)(Wb + (ft * 16 + mrow) * TWO_D + kt * 32 + quad * 8);
            accf[ft] = __builtin_amdgcn_mfma_f32_16x16x32_bf16(a[kt], b, accf[ft], 0, 0, 0);
        }
    }

    #pragma unroll
    for (int ft = 0; ft < 8; ++ft)
        #pragma unroll
        for (int r = 0; r < 4; ++r) accf[ft][r] += bi[ft];

    #pragma unroll
    for (int r = 0; r < 4; ++r) {
        float s = 0.f, s2 = 0.f;
        #pragma unroll
        for (int ft = 0; ft < 8; ++ft) {
            float x = accf[ft][r];
            s += x; s2 += x * x;
        }
        #pragma unroll
        for (int off = 1; off <= 8; off <<= 1) {
            s  += __shfl_xor(s,  off, 64);
            s2 += __shfl_xor(s2, off, 64);
        }
        float mu  = s * (1.0f / 128.0f);
        float var = s2 * (1.0f / 128.0f) - mu * mu;
        float ivn = rsqrtf(var + 1e-5f);
        int n = n0 + wave * 16 + quad * 4 + r;
        if (n < N) {
            #pragma unroll
            for (int ft = 0; ft < 8; ++ft) {
                int f = ft * 16 + mrow;
                out[(size_t)n * D + f] = (accf[ft][r] - mu) * ivn * gm[ft] + bt[ft];
            }
        }
    }
}

// ===========================================================================
// Tier C fallback (round-1 atomic path) if ws too small
// ===========================================================================
__global__ __launch_bounds__(256) void gcn_edge_attn(
    const float* __restrict__ emb, const int* __restrict__ edges,
    float* __restrict__ agg, float* __restrict__ denom, int E) {
    int e    = (int)((blockIdx.x * 256u + threadIdx.x) >> 6);
    int lane = threadIdx.x & 63;
    if (e >= E) return;
    int row = edges[e];
    int col = edges[E + e];
    const float2 a = *(const float2*)(emb + (size_t)row * D + lane * 2);
    const float2 c = *(const float2*)(emb + (size_t)col * D + lane * 2);
    float s = a.x * c.x + a.y * c.y;
    #pragma unroll
    for (int off = 32; off >= 1; off >>= 1) s += __shfl_xor(s, off, 64);
    float attn = expf(s);
    float* dst = agg + (size_t)row * D + lane * 2;
    unsafeAtomicAdd(dst,     attn * c.x);
    unsafeAtomicAdd(dst + 1, attn * c.y);
    if (lane == 0) unsafeAtomicAdd(denom + row, attn);
}

__global__ __launch_bounds__(256) void gcn_node_fallback(
    const float* __restrict__ emb, const float* __restrict__ W,
    const float* __restrict__ bias, const float* __restrict__ gamma,
    const float* __restrict__ beta, const float* __restrict__ denom,
    float* __restrict__ out, int N) {
    __shared__ float scat[2][TWO_D];
    __shared__ float sred[2][4];
    int tid  = threadIdx.x;
    int g    = tid >> 7;
    int o    = tid & 127;
    int lane = tid & 63;
    int wig  = (tid >> 6) & 1;
    for (int n0 = blockIdx.x * 2; n0 < N; n0 += gridDim.x * 2) {
        int n = n0 + g;
        bool act = (n < N);
        if (act) {
            float ev  = emb[(size_t)n * D + o];
            float inv = 1.0f / (denom[n] + 1e-20f);
            scat[g][o]     = ev;
            scat[g][D + o] = out[(size_t)n * D + o] * inv;
        }
        __syncthreads();
        float acc = 0.f;
        if (act) {
            const float4* wr = (const float4*)(W + (size_t)o * TWO_D);
            #pragma unroll 4
            for (int k4 = 0; k4 < TWO_D / 4; ++k4) {
                float4 w = wr[k4];
                float4 a = *(const float4*)(&scat[g][k4 * 4]);
                acc += w.x * a.x + w.y * a.y + w.z * a.z + w.w * a.w;
            }
            acc += bias[o];
        }
        float s = acc, s2 = acc * acc;
        #pragma unroll
        for (int off = 32; off >= 1; off >>= 1) {
            s  += __shfl_xor(s,  off, 64);
            s2 += __shfl_xor(s2, off, 64);
        }
        if (lane == 0) { sred[g][wig * 2] = s; sred[g][wig * 2 + 1] = s2; }
        __syncthreads();
        if (act) {
            float ts  = sred[g][0] + sred[g][2];
            float ts2 = sred[g][1] + sred[g][3];
            float mu  = ts * (1.0f / 128.0f);
            float var = ts2 * (1.0f / 128.0f) - mu * mu;
            float inv = rsqrtf(var + 1e-5f);
            out[(size_t)n * D + o] = (acc - mu) * inv * gamma[o] + beta[o];
        }
        __syncthreads();
    }
}

// ---------------------------------------------------------------------------
extern "C" void kernel_launch(void* const* d_in, const int* in_sizes, int n_in,
                              void* d_out, int out_size, void* d_ws, size_t ws_size,
                              hipStream_t stream) {
    const float* emb   = (const float*)d_in[0];
    const int*   edges = (const int*)  d_in[1];
    const float* W     = (const float*)d_in[2];
    const float* bias  = (const float*)d_in[3];
    const float* gamma = (const float*)d_in[4];
    const float* beta  = (const float*)d_in[5];
    float* out = (float*)d_out;

    int N = in_sizes[0] / D;        // 50000
    int E = in_sizes[1] / 2;        // 600000

    if (ws_size >= (size_t)WS_TIER_A) {
        char* ws = (char*)d_ws;
        int*            cnt    = (int*)            (ws + OFF_CNT);
        unsigned short* colbuf = (unsigned short*) (ws + OFF_COLBUF);
        unsigned int*   ccnt   = (unsigned int*)   (ws + OFF_CCNT);
        unsigned int*   coarse = (unsigned int*)   (ws + OFF_COARSE);
        __bf16*         Wb     = (__bf16*)         (ws + OFF_WBF16);
        __bf16*         embb   = (__bf16*)         (ws + OFF_EMBB);

        int nEmb8 = N * D / 8;                        // 800000
        int nW8   = D * TWO_D / 8;                    // 4096
        int cvtB  = (nEmb8 + nW8 + 255) / 256;        // 3142
        int binB  = (E + CHUNK - 1) / CHUNK;          // 293
        int NB    = (N + 255) >> 8;                   // 196

        hipMemsetAsync(ccnt, 0, 1024, stream);
        k_cvt_bin<<<binB + cvtB, 256, 0, stream>>>(
            emb, W, edges, embb, Wb, ccnt, coarse, nEmb8, nW8, E, binB, NB);
        k_fine   <<<NB, 256, 0, stream>>>(coarse, ccnt, cnt, colbuf, N);
        gcn_agg_b<<<(N + 15) / 16, 256, 0, stream>>>(embb, colbuf, cnt,
                                                     (__bf16*)out, N);
        gcn_node_b<<<(N + 63) / 64, 256, 0, stream>>>(embb, Wb, bias, gamma,
                                                      beta, out, N);
    } else {
        float* denom = (float*)d_ws;
        hipMemsetAsync(out,   0, (size_t)N * D * sizeof(float), stream);
        hipMemsetAsync(denom, 0, (size_t)N * sizeof(float), stream);
        gcn_edge_attn<<<(E + 3) / 4, 256, 0, stream>>>(emb, edges, out, denom, E);
        gcn_node_fallback<<<512, 256, 0, stream>>>(emb, W, bias, gamma, beta,
                                                   denom, out, N);
    }
}